// Round 2
// baseline (516.066 us; speedup 1.0000x reference)
//
#include <hip/hip_runtime.h>
#include <math.h>

#define L_DIM 2048
#define B_DIM 64
#define D_DIM 512
#define A_DIM 64

// ---------------------------------------------------------------------------
// Kernel A: hb[b][a] = b_attn[a] + sum_d hidden[b][d] * W_hidden[d][a]
// 64 blocks (b) x 64 threads (a). Tiny.
// ---------------------------------------------------------------------------
__global__ void hb_kernel(const float* __restrict__ hidden,
                          const float* __restrict__ Wh,
                          const float* __restrict__ battn,
                          float* __restrict__ hb) {
    const int b = blockIdx.x;
    const int a = threadIdx.x;
    const float* hrow = hidden + b * D_DIM;
    float acc = battn[a];
#pragma unroll 8
    for (int d = 0; d < D_DIM; ++d) {
        acc += hrow[d] * Wh[d * A_DIM + a];
    }
    hb[b * A_DIM + a] = acc;
}

// ---------------------------------------------------------------------------
// Kernel B: per-l block. GEMM tile 64(b) x 64(a) x K=512, then fused
// tanh(parts + hb) . v reduction -> masked score -> scores[b*L + l].
// 256 threads: thread (ty,tx) owns rows b = ty*4..+3, cols a = tx*4..+3.
// K-tiled by 32 with register prefetch of the next tile.
// ---------------------------------------------------------------------------
__global__ __launch_bounds__(256) void scores_kernel(
    const float* __restrict__ enc, const float* __restrict__ We,
    const float* __restrict__ hb, const float* __restrict__ v,
    const int* __restrict__ lens, float* __restrict__ scores) {
    const int l = blockIdx.x;
    const int tid = threadIdx.x;
    const int ty = tid >> 4;   // 0..15
    const int tx = tid & 15;   // 0..15

    __shared__ float As[32][68];   // As[k][b]  (transposed A tile, +4 pad)
    __shared__ float Bs[32][68];   // Bs[k][a]
    __shared__ float red[64][17];  // score partials [b][tx]

    float acc[4][4] = {};

    // A load map: chunk c = tid + 256*i, c in 0..511: b = c>>3, kq = c&7
    //   -> float4 at enc[(l*64+b)*512 + k0 + kq*4]  (fully coalesced)
    // B load map: chunk c: k = c>>4, a4 = (c&15)*4
    //   -> float4 at We[(k0+k)*64 + a4]             (fully coalesced)
    float4 areg[2], breg[2];

    const float* encl = enc + (size_t)l * B_DIM * D_DIM;

    auto loadTiles = [&](int k0) {
#pragma unroll
        for (int i = 0; i < 2; ++i) {
            const int c = tid + 256 * i;
            const int bb = c >> 3, kq = c & 7;
            areg[i] = *(const float4*)(encl + bb * D_DIM + k0 + kq * 4);
            const int kk = c >> 4, a4 = (c & 15) * 4;
            breg[i] = *(const float4*)(We + (k0 + kk) * A_DIM + a4);
        }
    };
    auto storeTiles = [&]() {
#pragma unroll
        for (int i = 0; i < 2; ++i) {
            const int c = tid + 256 * i;
            const int bb = c >> 3, kq = c & 7;
            As[kq * 4 + 0][bb] = areg[i].x;
            As[kq * 4 + 1][bb] = areg[i].y;
            As[kq * 4 + 2][bb] = areg[i].z;
            As[kq * 4 + 3][bb] = areg[i].w;
            const int kk = c >> 4, a4 = (c & 15) * 4;
            *(float4*)&Bs[kk][a4] = breg[i];
        }
    };

    loadTiles(0);
#pragma unroll 1
    for (int t = 0; t < 16; ++t) {
        __syncthreads();           // previous tile's LDS reads complete
        storeTiles();
        __syncthreads();           // tile visible
        if (t < 15) loadTiles((t + 1) * 32);  // prefetch next (regs free now)
#pragma unroll
        for (int k = 0; k < 32; ++k) {
            const float4 av = *(const float4*)&As[k][ty * 4];
            const float4 bv = *(const float4*)&Bs[k][tx * 4];
            acc[0][0] += av.x * bv.x; acc[0][1] += av.x * bv.y;
            acc[0][2] += av.x * bv.z; acc[0][3] += av.x * bv.w;
            acc[1][0] += av.y * bv.x; acc[1][1] += av.y * bv.y;
            acc[1][2] += av.y * bv.z; acc[1][3] += av.y * bv.w;
            acc[2][0] += av.z * bv.x; acc[2][1] += av.z * bv.y;
            acc[2][2] += av.z * bv.z; acc[2][3] += av.z * bv.w;
            acc[3][0] += av.w * bv.x; acc[3][1] += av.w * bv.y;
            acc[3][2] += av.w * bv.z; acc[3][3] += av.w * bv.w;
        }
    }

    // Epilogue: tanh(parts + hb) . v, partial over this thread's 4 a-cols
    const float4 vv = *(const float4*)(v + tx * 4);
#pragma unroll
    for (int i = 0; i < 4; ++i) {
        const int bb = ty * 4 + i;
        const float4 hbv = *(const float4*)(hb + bb * A_DIM + tx * 4);
        float s = tanhf(acc[i][0] + hbv.x) * vv.x;
        s += tanhf(acc[i][1] + hbv.y) * vv.y;
        s += tanhf(acc[i][2] + hbv.z) * vv.z;
        s += tanhf(acc[i][3] + hbv.w) * vv.w;
        red[bb][tx] = s;
    }
    __syncthreads();
    if (tid < B_DIM) {
        const int bb = tid;
        float s = 0.f;
#pragma unroll
        for (int j = 0; j < 16; ++j) s += red[bb][j];
        // faithful mask: +1 where valid, -inf at padding
        s = (l < lens[bb]) ? (s + 1.0f) : -INFINITY;
        scores[(size_t)bb * L_DIM + l] = s;
    }
}

// ---------------------------------------------------------------------------
// Kernel C1: per-b masked softmax over L (in place on scores[b*L + l]).
// ---------------------------------------------------------------------------
__global__ __launch_bounds__(256) void softmax_kernel(float* __restrict__ scores) {
    const int b = blockIdx.x;
    const int tid = threadIdx.x;
    float* s = scores + (size_t)b * L_DIM;
    __shared__ float red[256];

    float m = -INFINITY;
    for (int l = tid; l < L_DIM; l += 256) m = fmaxf(m, s[l]);
    red[tid] = m;
    __syncthreads();
    for (int off = 128; off > 0; off >>= 1) {
        if (tid < off) red[tid] = fmaxf(red[tid], red[tid + off]);
        __syncthreads();
    }
    m = red[0];
    __syncthreads();

    float z = 0.f;
    for (int l = tid; l < L_DIM; l += 256) z += expf(s[l] - m);
    red[tid] = z;
    __syncthreads();
    for (int off = 128; off > 0; off >>= 1) {
        if (tid < off) red[tid] += red[tid + off];
        __syncthreads();
    }
    const float inv = 1.0f / red[0];

    for (int l = tid; l < L_DIM; l += 256) s[l] = expf(s[l] - m) * inv;
}

// ---------------------------------------------------------------------------
// Kernel C2a: zero-init d_out (harness poisons it with 0xAA before each call)
// ---------------------------------------------------------------------------
__global__ __launch_bounds__(256) void zero_out_kernel(float* __restrict__ out) {
    out[blockIdx.x * 256 + threadIdx.x] = 0.f;
}

// ---------------------------------------------------------------------------
// Kernel C2b: weighted sum. Grid (b=64, lc=16), 128 threads (= 512/4 float4
// lanes, exact D coverage). Each block accumulates 128 l values in registers,
// then one atomicAdd per output float (16-way contention per address).
// ---------------------------------------------------------------------------
__global__ __launch_bounds__(128) void wsum_kernel(
    const float* __restrict__ enc, const float* __restrict__ w,
    float* __restrict__ out) {
    const int b = blockIdx.x;
    const int lc = blockIdx.y;
    const int tid = threadIdx.x;           // 0..127, d = tid*4
    const int l0 = lc * (L_DIM / 16);

    float4 acc = {0.f, 0.f, 0.f, 0.f};
#pragma unroll 4
    for (int l = l0; l < l0 + (L_DIM / 16); ++l) {
        const float wt = w[(size_t)b * L_DIM + l];   // uniform -> scalar load
        const float4 e =
            *(const float4*)(enc + ((size_t)l * B_DIM + b) * D_DIM + tid * 4);
        acc.x += wt * e.x; acc.y += wt * e.y;
        acc.z += wt * e.z; acc.w += wt * e.w;
    }
    float* o = out + (size_t)b * D_DIM + tid * 4;
    atomicAdd(o + 0, acc.x);
    atomicAdd(o + 1, acc.y);
    atomicAdd(o + 2, acc.z);
    atomicAdd(o + 3, acc.w);
}

extern "C" void kernel_launch(void* const* d_in, const int* in_sizes, int n_in,
                              void* d_out, int out_size, void* d_ws, size_t ws_size,
                              hipStream_t stream) {
    const float* enc    = (const float*)d_in[0];  // (L, B, 512)
    const int*   lens   = (const int*)d_in[1];    // (B,)
    const float* hidden = (const float*)d_in[2];  // (B, 512)
    const float* We     = (const float*)d_in[3];  // (512, 64)
    const float* battn  = (const float*)d_in[4];  // (64,)
    const float* Wh     = (const float*)d_in[5];  // (512, 64)
    const float* v      = (const float*)d_in[6];  // (64,)
    float* out = (float*)d_out;                   // (B, 512) = 32768 floats

    // ws layout (floats): hb[64*64] | scores[64*2048]  -> ~540 KB total
    float* hb     = (float*)d_ws;
    float* scores = hb + B_DIM * A_DIM;

    hb_kernel<<<B_DIM, A_DIM, 0, stream>>>(hidden, Wh, battn, hb);
    scores_kernel<<<L_DIM, 256, 0, stream>>>(enc, We, hb, v, lens, scores);
    softmax_kernel<<<B_DIM, 256, 0, stream>>>(scores);
    zero_out_kernel<<<(B_DIM * D_DIM) / 256, 256, 0, stream>>>(out);
    wsum_kernel<<<dim3(B_DIM, 16), 128, 0, stream>>>(enc, scores, out);
}

// Round 3
// 509.076 us; speedup vs baseline: 1.0137x; 1.0137x over previous
//
#include <hip/hip_runtime.h>
#include <hip/hip_bf16.h>
#include <math.h>

#define L_DIM 2048
#define B_DIM 64
#define D_DIM 512
#define A_DIM 64

#define CHUNK_L 64   // l's per fused block (2 sub-chunks)
#define SUB_L 32     // l's per sub-chunk resident in LDS
#define N_CHUNK (L_DIM / CHUNK_L)   // 32 chunks per batch column
#define EPAD 520     // LDS row pitch in bf16 elems (512 + 8 pad -> 2-way banks)

typedef __attribute__((ext_vector_type(8))) short bf16x8;
typedef __attribute__((ext_vector_type(4))) float f32x4;

__device__ __forceinline__ void split_bf16(float x, short& hi, short& lo) {
    __hip_bfloat16 h = __float2bfloat16(x);
    float hf = __bfloat162float(h);
    __hip_bfloat16 l = __float2bfloat16(x - hf);
    hi = *reinterpret_cast<short*>(&h);
    lo = *reinterpret_cast<short*>(&l);
}
__device__ __forceinline__ float bf16s_to_f(short s) {
    unsigned int u = ((unsigned int)(unsigned short)s) << 16;
    return __uint_as_float(u);
}

// ---------------------------------------------------------------------------
// Setup A: hb[b][a] = b_attn[a] + hidden[b] . W_hidden[:,a]
// ---------------------------------------------------------------------------
__global__ void hb_kernel(const float* __restrict__ hidden,
                          const float* __restrict__ Wh,
                          const float* __restrict__ battn,
                          float* __restrict__ hb) {
    const int b = blockIdx.x;
    const int a = threadIdx.x;
    const float* hrow = hidden + b * D_DIM;
    float acc = battn[a];
#pragma unroll 8
    for (int d = 0; d < D_DIM; ++d) acc += hrow[d] * Wh[d * A_DIM + a];
    hb[b * A_DIM + a] = acc;
}

// ---------------------------------------------------------------------------
// Setup B: transpose + split We (512x64 f32) -> Wt_hi/Wt_lo (64x512 bf16)
// ---------------------------------------------------------------------------
__global__ __launch_bounds__(256) void wt_kernel(const float* __restrict__ We,
                                                 short* __restrict__ wt_hi,
                                                 short* __restrict__ wt_lo) {
    const int idx = blockIdx.x * 256 + threadIdx.x;  // 0..32767
    const int a = idx & 63;
    const int d = idx >> 6;
    float x = We[d * A_DIM + a];
    short h, l;
    split_bf16(x, h, l);
    wt_hi[a * D_DIM + d] = h;
    wt_lo[a * D_DIM + d] = l;
}

// ---------------------------------------------------------------------------
// Fused kernel: grid (chunk=32, b=64), 256 threads (4 waves).
// Per sub-chunk of 32 l's: stage enc->LDS split-bf16, MFMA GEMM P=E@We,
// scores=1+tanh(P+hb).v (masked), chunk-local online softmax, weighted
// accumulation of enc rows from LDS. Writes per-chunk partials (O, m, Z).
// ---------------------------------------------------------------------------
__global__ __launch_bounds__(256) void fused_kernel(
    const float* __restrict__ enc, const short* __restrict__ wt_hi,
    const short* __restrict__ wt_lo, const float* __restrict__ hb,
    const float* __restrict__ v, const int* __restrict__ lens,
    float* __restrict__ Om, float* __restrict__ mz) {
    const int c = blockIdx.x;      // chunk 0..31
    const int b = blockIdx.y;      // batch 0..63
    const int tid = threadIdx.x;
    const int wave = tid >> 6;
    const int lane = tid & 63;
    const int quad = lane >> 4;
    const int l15 = lane & 15;

    __shared__ short Ehi[SUB_L][EPAD];
    __shared__ short Elo[SUB_L][EPAD];
    __shared__ float sred[SUB_L][2];
    __shared__ float wl[SUB_L];
    __shared__ float red[4][D_DIM];
    __shared__ float msc[2];

    const int len_b = lens[b];

    // wave tile assignment: l-tile = wave>>1 (16 rows), a-half = wave&1
    const int lt = wave >> 1;
    const int ah = wave & 1;
    const int a0 = (2 * ah) * 16 + l15;   // col for acc0
    const int a1 = a0 + 16;               // col for acc1

    const float hb0 = hb[b * A_DIM + a0];
    const float hb1 = hb[b * A_DIM + a1];
    const float v0 = v[a0];
    const float v1 = v[a1];

    float Oacc[8];
#pragma unroll
    for (int i = 0; i < 8; ++i) Oacc[i] = 0.f;
    float mA = -INFINITY, ZA = 0.f;

    const int g = tid >> 6;           // accumulation l-group (== wave)
    const int d0 = (tid & 63) * 8;    // accumulation d-base

#pragma unroll 1
    for (int sub = 0; sub < 2; ++sub) {
        const int l_base = c * CHUNK_L + sub * SUB_L;

        __syncthreads();  // protect LDS from previous iteration's readers

        // ---- Phase 1: stage 32 enc rows (fp32) -> split bf16 in LDS ----
        {
            const float* src = enc + ((size_t)l_base * B_DIM + b) * D_DIM;
#pragma unroll
            for (int j = 0; j < 16; ++j) {
                const int idx = tid + 256 * j;   // float4 index 0..4095
                const int li = idx >> 7;         // row 0..31
                const int po = idx & 127;        // float4 within row
                const float4 x =
                    *(const float4*)(src + (size_t)li * B_DIM * D_DIM + po * 4);
                short4 h4, l4;
                split_bf16(x.x, h4.x, l4.x);
                split_bf16(x.y, h4.y, l4.y);
                split_bf16(x.z, h4.z, l4.z);
                split_bf16(x.w, h4.w, l4.w);
                *(short4*)&Ehi[li][po * 4] = h4;
                *(short4*)&Elo[li][po * 4] = l4;
            }
        }
        __syncthreads();

        // ---- Phase 2: MFMA GEMM. P[l][a] = sum_d E[l][d]*We[d][a] ----
        f32x4 acc0 = {0.f, 0.f, 0.f, 0.f};
        f32x4 acc1 = {0.f, 0.f, 0.f, 0.f};
        const short* brow0h = wt_hi + (size_t)a0 * D_DIM + quad * 8;
        const short* brow0l = wt_lo + (size_t)a0 * D_DIM + quad * 8;
        const short* brow1h = wt_hi + (size_t)a1 * D_DIM + quad * 8;
        const short* brow1l = wt_lo + (size_t)a1 * D_DIM + quad * 8;
        const int arow = lt * 16 + l15;
#pragma unroll 4
        for (int s = 0; s < 16; ++s) {
            const int k = s * 32;
            const bf16x8 Ah = *(const bf16x8*)&Ehi[arow][k + quad * 8];
            const bf16x8 Al = *(const bf16x8*)&Elo[arow][k + quad * 8];
            const bf16x8 B0h = *(const bf16x8*)(brow0h + k);
            const bf16x8 B0l = *(const bf16x8*)(brow0l + k);
            const bf16x8 B1h = *(const bf16x8*)(brow1h + k);
            const bf16x8 B1l = *(const bf16x8*)(brow1l + k);
            acc0 = __builtin_amdgcn_mfma_f32_16x16x32_bf16(Ah, B0h, acc0, 0, 0, 0);
            acc0 = __builtin_amdgcn_mfma_f32_16x16x32_bf16(Ah, B0l, acc0, 0, 0, 0);
            acc0 = __builtin_amdgcn_mfma_f32_16x16x32_bf16(Al, B0h, acc0, 0, 0, 0);
            acc1 = __builtin_amdgcn_mfma_f32_16x16x32_bf16(Ah, B1h, acc1, 0, 0, 0);
            acc1 = __builtin_amdgcn_mfma_f32_16x16x32_bf16(Ah, B1l, acc1, 0, 0, 0);
            acc1 = __builtin_amdgcn_mfma_f32_16x16x32_bf16(Al, B1h, acc1, 0, 0, 0);
        }

        // ---- Phase 3: scores. C/D layout: col=lane&15, row=quad*4+reg ----
#pragma unroll
        for (int r = 0; r < 4; ++r) {
            float t = tanhf(acc0[r] + hb0) * v0 + tanhf(acc1[r] + hb1) * v1;
            t += __shfl_xor(t, 1);
            t += __shfl_xor(t, 2);
            t += __shfl_xor(t, 4);
            t += __shfl_xor(t, 8);
            if (l15 == 0) sred[lt * 16 + quad * 4 + r][ah] = t;
        }
        __syncthreads();

        if (tid < 32) {
            const int lg = l_base + tid;
            float s = sred[tid][0] + sred[tid][1];
            s = (lg < len_b) ? (s + 1.0f) : -INFINITY;
            float m = s;
            m = fmaxf(m, __shfl_xor(m, 1));
            m = fmaxf(m, __shfl_xor(m, 2));
            m = fmaxf(m, __shfl_xor(m, 4));
            m = fmaxf(m, __shfl_xor(m, 8));
            m = fmaxf(m, __shfl_xor(m, 16));
            const float w = (m == -INFINITY) ? 0.f : expf(s - m);
            wl[tid] = w;
            float z = w;
            z += __shfl_xor(z, 1);
            z += __shfl_xor(z, 2);
            z += __shfl_xor(z, 4);
            z += __shfl_xor(z, 8);
            z += __shfl_xor(z, 16);
            if (tid == 0) { msc[0] = m; msc[1] = z; }
        }
        __syncthreads();

        // ---- Phase 4: weighted accumulation from LDS ----
        float pa[8];
#pragma unroll
        for (int i = 0; i < 8; ++i) pa[i] = 0.f;
#pragma unroll
        for (int li = 0; li < 8; ++li) {
            const int l = g * 8 + li;
            const float w = wl[l];
            const bf16x8 h8 = *(const bf16x8*)&Ehi[l][d0];
            const bf16x8 l8 = *(const bf16x8*)&Elo[l][d0];
#pragma unroll
            for (int i = 0; i < 8; ++i) {
                pa[i] += w * (bf16s_to_f(h8[i]) + bf16s_to_f(l8[i]));
            }
        }
        *(float4*)&red[g][d0] = make_float4(pa[0], pa[1], pa[2], pa[3]);
        *(float4*)&red[g][d0 + 4] = make_float4(pa[4], pa[5], pa[6], pa[7]);
        __syncthreads();

        // ---- Phase 5: merge sub-chunk into running online-softmax state ----
        const float m_sub = msc[0], Z_sub = msc[1];
        const float mN = fmaxf(mA, m_sub);
        const float cA = (mA == -INFINITY) ? 0.f : expf(mA - mN);
        const float cS = (m_sub == -INFINITY) ? 0.f : expf(m_sub - mN);
        if (tid < 64) {
            const int dd = tid * 8;
#pragma unroll
            for (int i = 0; i < 8; ++i) {
                const float os =
                    red[0][dd + i] + red[1][dd + i] + red[2][dd + i] + red[3][dd + i];
                Oacc[i] = cA * Oacc[i] + cS * os;
            }
        }
        ZA = cA * ZA + cS * Z_sub;
        mA = mN;
    }

    // ---- write chunk partials ----
    if (tid < 64) {
        float* dst = Om + ((size_t)b * N_CHUNK + c) * D_DIM + tid * 8;
        *(float4*)dst = make_float4(Oacc[0], Oacc[1], Oacc[2], Oacc[3]);
        *(float4*)(dst + 4) = make_float4(Oacc[4], Oacc[5], Oacc[6], Oacc[7]);
    }
    if (tid == 0) {
        mz[((size_t)b * N_CHUNK + c) * 2 + 0] = mA;
        mz[((size_t)b * N_CHUNK + c) * 2 + 1] = ZA;
    }
}

// ---------------------------------------------------------------------------
// Combine: merge 32 chunk partials per b -> out[b][d]
// ---------------------------------------------------------------------------
__global__ __launch_bounds__(256) void combine_kernel(
    const float* __restrict__ Om, const float* __restrict__ mz,
    float* __restrict__ out) {
    const int b = blockIdx.x;
    const int tid = threadIdx.x;
    __shared__ float coef[N_CHUNK];
    __shared__ float sinv;

    if (tid < 32) {
        const float m = mz[((size_t)b * N_CHUNK + tid) * 2 + 0];
        const float Z = mz[((size_t)b * N_CHUNK + tid) * 2 + 1];
        float mm = m;
        mm = fmaxf(mm, __shfl_xor(mm, 1));
        mm = fmaxf(mm, __shfl_xor(mm, 2));
        mm = fmaxf(mm, __shfl_xor(mm, 4));
        mm = fmaxf(mm, __shfl_xor(mm, 8));
        mm = fmaxf(mm, __shfl_xor(mm, 16));
        const float cc = (m == -INFINITY) ? 0.f : expf(m - mm);
        coef[tid] = cc;
        float s = cc * Z;
        s += __shfl_xor(s, 1);
        s += __shfl_xor(s, 2);
        s += __shfl_xor(s, 4);
        s += __shfl_xor(s, 8);
        s += __shfl_xor(s, 16);
        if (tid == 0) sinv = 1.0f / s;
    }
    __syncthreads();

    const float* base = Om + (size_t)b * N_CHUNK * D_DIM + tid * 2;
    float ox = 0.f, oy = 0.f;
#pragma unroll 8
    for (int cc = 0; cc < N_CHUNK; ++cc) {
        const float2 x = *(const float2*)(base + cc * D_DIM);
        ox += coef[cc] * x.x;
        oy += coef[cc] * x.y;
    }
    const float s = sinv;
    *(float2*)(out + (size_t)b * D_DIM + tid * 2) = make_float2(ox * s, oy * s);
}

// ===========================================================================
// Fallback path (round-2 proven): used only if ws_size is too small
// ===========================================================================
__global__ __launch_bounds__(256) void scores_kernel(
    const float* __restrict__ enc, const float* __restrict__ We,
    const float* __restrict__ hb, const float* __restrict__ v,
    const int* __restrict__ lens, float* __restrict__ scores) {
    const int l = blockIdx.x;
    const int tid = threadIdx.x;
    const int ty = tid >> 4;
    const int tx = tid & 15;

    __shared__ float As[32][68];
    __shared__ float Bs[32][68];
    __shared__ float redl[64][17];

    float acc[4][4] = {};
    float4 areg[2], breg[2];
    const float* encl = enc + (size_t)l * B_DIM * D_DIM;

    auto loadTiles = [&](int k0) {
#pragma unroll
        for (int i = 0; i < 2; ++i) {
            const int cc = tid + 256 * i;
            const int bb = cc >> 3, kq = cc & 7;
            areg[i] = *(const float4*)(encl + bb * D_DIM + k0 + kq * 4);
            const int kk = cc >> 4, a4 = (cc & 15) * 4;
            breg[i] = *(const float4*)(We + (k0 + kk) * A_DIM + a4);
        }
    };
    auto storeTiles = [&]() {
#pragma unroll
        for (int i = 0; i < 2; ++i) {
            const int cc = tid + 256 * i;
            const int bb = cc >> 3, kq = cc & 7;
            As[kq * 4 + 0][bb] = areg[i].x;
            As[kq * 4 + 1][bb] = areg[i].y;
            As[kq * 4 + 2][bb] = areg[i].z;
            As[kq * 4 + 3][bb] = areg[i].w;
            const int kk = cc >> 4, a4 = (cc & 15) * 4;
            *(float4*)&Bs[kk][a4] = breg[i];
        }
    };

    loadTiles(0);
#pragma unroll 1
    for (int t = 0; t < 16; ++t) {
        __syncthreads();
        storeTiles();
        __syncthreads();
        if (t < 15) loadTiles((t + 1) * 32);
#pragma unroll
        for (int k = 0; k < 32; ++k) {
            const float4 av = *(const float4*)&As[k][ty * 4];
            const float4 bv = *(const float4*)&Bs[k][tx * 4];
            acc[0][0] += av.x * bv.x; acc[0][1] += av.x * bv.y;
            acc[0][2] += av.x * bv.z; acc[0][3] += av.x * bv.w;
            acc[1][0] += av.y * bv.x; acc[1][1] += av.y * bv.y;
            acc[1][2] += av.y * bv.z; acc[1][3] += av.y * bv.w;
            acc[2][0] += av.z * bv.x; acc[2][1] += av.z * bv.y;
            acc[2][2] += av.z * bv.z; acc[2][3] += av.z * bv.w;
            acc[3][0] += av.w * bv.x; acc[3][1] += av.w * bv.y;
            acc[3][2] += av.w * bv.z; acc[3][3] += av.w * bv.w;
        }
    }

    const float4 vv = *(const float4*)(v + tx * 4);
#pragma unroll
    for (int i = 0; i < 4; ++i) {
        const int bb = ty * 4 + i;
        const float4 hbv = *(const float4*)(hb + bb * A_DIM + tx * 4);
        float s = tanhf(acc[i][0] + hbv.x) * vv.x;
        s += tanhf(acc[i][1] + hbv.y) * vv.y;
        s += tanhf(acc[i][2] + hbv.z) * vv.z;
        s += tanhf(acc[i][3] + hbv.w) * vv.w;
        redl[bb][tx] = s;
    }
    __syncthreads();
    if (tid < B_DIM) {
        const int bb = tid;
        float s = 0.f;
#pragma unroll
        for (int j = 0; j < 16; ++j) s += redl[bb][j];
        s = (l < lens[bb]) ? (s + 1.0f) : -INFINITY;
        scores[(size_t)bb * L_DIM + l] = s;
    }
}

__global__ __launch_bounds__(256) void softmax_kernel(float* __restrict__ scores) {
    const int b = blockIdx.x;
    const int tid = threadIdx.x;
    float* s = scores + (size_t)b * L_DIM;
    __shared__ float red[256];

    float m = -INFINITY;
    for (int l = tid; l < L_DIM; l += 256) m = fmaxf(m, s[l]);
    red[tid] = m;
    __syncthreads();
    for (int off = 128; off > 0; off >>= 1) {
        if (tid < off) red[tid] = fmaxf(red[tid], red[tid + off]);
        __syncthreads();
    }
    m = red[0];
    __syncthreads();

    float z = 0.f;
    for (int l = tid; l < L_DIM; l += 256) z += expf(s[l] - m);
    red[tid] = z;
    __syncthreads();
    for (int off = 128; off > 0; off >>= 1) {
        if (tid < off) red[tid] += red[tid + off];
        __syncthreads();
    }
    const float inv = 1.0f / red[0];
    for (int l = tid; l < L_DIM; l += 256) s[l] = expf(s[l] - m) * inv;
}

__global__ __launch_bounds__(256) void zero_out_kernel(float* __restrict__ out) {
    out[blockIdx.x * 256 + threadIdx.x] = 0.f;
}

__global__ __launch_bounds__(128) void wsum_kernel(
    const float* __restrict__ enc, const float* __restrict__ w,
    float* __restrict__ out) {
    const int b = blockIdx.x;
    const int lc = blockIdx.y;
    const int tid = threadIdx.x;
    const int l0 = lc * (L_DIM / 16);

    float4 acc = {0.f, 0.f, 0.f, 0.f};
#pragma unroll 4
    for (int l = l0; l < l0 + (L_DIM / 16); ++l) {
        const float wt = w[(size_t)b * L_DIM + l];
        const float4 e =
            *(const float4*)(enc + ((size_t)l * B_DIM + b) * D_DIM + tid * 4);
        acc.x += wt * e.x; acc.y += wt * e.y;
        acc.z += wt * e.z; acc.w += wt * e.w;
    }
    float* o = out + (size_t)b * D_DIM + tid * 4;
    atomicAdd(o + 0, acc.x);
    atomicAdd(o + 1, acc.y);
    atomicAdd(o + 2, acc.z);
    atomicAdd(o + 3, acc.w);
}

// ===========================================================================
extern "C" void kernel_launch(void* const* d_in, const int* in_sizes, int n_in,
                              void* d_out, int out_size, void* d_ws, size_t ws_size,
                              hipStream_t stream) {
    const float* enc    = (const float*)d_in[0];
    const int*   lens   = (const int*)d_in[1];
    const float* hidden = (const float*)d_in[2];
    const float* We     = (const float*)d_in[3];
    const float* battn  = (const float*)d_in[4];
    const float* Wh     = (const float*)d_in[5];
    const float* v      = (const float*)d_in[6];
    float* out = (float*)d_out;

    // fused-path ws layout (bytes):
    //   hb     @ 0       (16 KB)
    //   wt_hi  @ 16K     (64 KB, bf16)
    //   wt_lo  @ 80K     (64 KB, bf16)
    //   mz     @ 144K    (16 KB)
    //   Om     @ 160K    (4 MB)
    const size_t NEED = (size_t)160 * 1024 + (size_t)4 * 1024 * 1024;

    if (ws_size >= NEED) {
        char* w8 = (char*)d_ws;
        float* hb    = (float*)(w8 + 0);
        short* wt_hi = (short*)(w8 + 16 * 1024);
        short* wt_lo = (short*)(w8 + 80 * 1024);
        float* mz    = (float*)(w8 + 144 * 1024);
        float* Om    = (float*)(w8 + 160 * 1024);

        hb_kernel<<<B_DIM, A_DIM, 0, stream>>>(hidden, Wh, battn, hb);
        wt_kernel<<<(D_DIM * A_DIM) / 256, 256, 0, stream>>>(We, wt_hi, wt_lo);
        fused_kernel<<<dim3(N_CHUNK, B_DIM), 256, 0, stream>>>(
            enc, wt_hi, wt_lo, hb, v, lens, Om, mz);
        combine_kernel<<<B_DIM, 256, 0, stream>>>(Om, mz, out);
    } else {
        float* hb     = (float*)d_ws;
        float* scores = hb + B_DIM * A_DIM;

        hb_kernel<<<B_DIM, A_DIM, 0, stream>>>(hidden, Wh, battn, hb);
        scores_kernel<<<L_DIM, 256, 0, stream>>>(enc, We, hb, v, lens, scores);
        softmax_kernel<<<B_DIM, 256, 0, stream>>>(scores);
        zero_out_kernel<<<(B_DIM * D_DIM) / 256, 256, 0, stream>>>(out);
        wsum_kernel<<<dim3(B_DIM, 16), 128, 0, stream>>>(enc, scores, out);
    }
}

// Round 4
// 498.081 us; speedup vs baseline: 1.0361x; 1.0221x over previous
//
#include <hip/hip_runtime.h>
#include <hip/hip_bf16.h>
#include <math.h>

#define L_DIM 2048
#define B_DIM 64
#define D_DIM 512
#define A_DIM 64

#define SUB_L 16                      // l's resident in LDS per phase
#define CHUNK_L 64                    // l's per block
#define N_SUB (CHUNK_L / SUB_L)       // 4
#define N_CHUNK (L_DIM / CHUNK_L)     // 32
#define EPAD 520                      // bf16 row pitch (1040 B, 16B-aligned)

typedef __attribute__((ext_vector_type(8))) short bf16x8;
typedef __attribute__((ext_vector_type(4))) float f32x4;

__device__ __forceinline__ void split_bf16(float x, short& hi, short& lo) {
    __hip_bfloat16 h = __float2bfloat16(x);
    float hf = __bfloat162float(h);
    __hip_bfloat16 l = __float2bfloat16(x - hf);
    hi = *reinterpret_cast<short*>(&h);
    lo = *reinterpret_cast<short*>(&l);
}

__device__ __forceinline__ void split4(const float4& x, short4& h, short4& l) {
    split_bf16(x.x, h.x, l.x);
    split_bf16(x.y, h.y, l.y);
    split_bf16(x.z, h.z, l.z);
    split_bf16(x.w, h.w, l.w);
}

// ---------------------------------------------------------------------------
// Setup A: hb[b][a] = b_attn[a] + hidden[b] . W_hidden[:,a]
// ---------------------------------------------------------------------------
__global__ void hb_kernel(const float* __restrict__ hidden,
                          const float* __restrict__ Wh,
                          const float* __restrict__ battn,
                          float* __restrict__ hb) {
    const int b = blockIdx.x;
    const int a = threadIdx.x;
    const float* hrow = hidden + b * D_DIM;
    float acc = battn[a];
#pragma unroll 8
    for (int d = 0; d < D_DIM; ++d) acc += hrow[d] * Wh[d * A_DIM + a];
    hb[b * A_DIM + a] = acc;
}

// ---------------------------------------------------------------------------
// Setup B: transpose + split We (512x64 f32) -> wt_hi/wt_lo (64x512 bf16)
// ---------------------------------------------------------------------------
__global__ __launch_bounds__(256) void wt_kernel(const float* __restrict__ We,
                                                 short* __restrict__ wt_hi,
                                                 short* __restrict__ wt_lo) {
    const int idx = blockIdx.x * 256 + threadIdx.x;  // 0..32767
    const int a = idx & 63;
    const int d = idx >> 6;
    float x = We[d * A_DIM + a];
    short h, l;
    split_bf16(x, h, l);
    wt_hi[a * D_DIM + d] = h;
    wt_lo[a * D_DIM + d] = l;
}

// ---------------------------------------------------------------------------
// Fused kernel v2: grid (chunk=32, b=64), 256 threads (4 waves).
// Per sub-chunk of 16 l's:
//   - stage enc rows (fp32 kept in REGISTERS) -> split-bf16 into LDS
//   - prefetch next sub-chunk's global loads (overlap with MFMA)
//   - MFMA 16x16x32 x3 (split product) over K=512; each wave owns 16 a-cols
//   - scores = 1 + tanh(P+hb).v (masked), sub-chunk online softmax
//   - weighted accumulation straight from the fp32 registers
// Per-thread output state: one float4 (d-slice po*4), merged across the two
// l-parity halves at block end. Writes per-chunk partials (O, m, Z).
// ---------------------------------------------------------------------------
__global__ __launch_bounds__(256) void fused_kernel(
    const float* __restrict__ enc, const short* __restrict__ wt_hi,
    const short* __restrict__ wt_lo, const float* __restrict__ hb,
    const float* __restrict__ v, const int* __restrict__ lens,
    float* __restrict__ Om, float* __restrict__ mz) {
    const int c = blockIdx.x;      // chunk 0..31
    const int b = blockIdx.y;      // batch 0..63
    const int tid = threadIdx.x;
    const int wave = tid >> 6;     // 0..3  (a-tile)
    const int lane = tid & 63;
    const int quad = lane >> 4;    // 0..3
    const int l15 = lane & 15;
    const int po = tid & 127;      // float4 column 0..127 (d = po*4)
    const int par = tid >> 7;      // l-parity 0/1

    __shared__ short Ehi[SUB_L][EPAD];   // 16.6 KB
    __shared__ short Elo[SUB_L][EPAD];   // 16.6 KB
    __shared__ float sred[SUB_L][4];
    __shared__ float wl[SUB_L];
    __shared__ float msc[2];
    __shared__ float ored[D_DIM];        // 2 KB (parity merge)

    const int len_b = lens[b];
    const int a_col = wave * 16 + l15;
    const float hb0 = hb[b * A_DIM + a_col];
    const float v0 = v[a_col];

    float4 Oacc = {0.f, 0.f, 0.f, 0.f};
    float mA = -INFINITY, ZA = 0.f;

    // base pointer for this (c, b): rows li offset by li * B*D floats
    const float* encb = enc + (size_t)c * CHUNK_L * B_DIM * D_DIM +
                        (size_t)b * D_DIM + po * 4;
    const size_t ROWSTRIDE = (size_t)B_DIM * D_DIM;

    float4 cur[8], nxt[8];
#pragma unroll
    for (int j = 0; j < 8; ++j)
        cur[j] = *(const float4*)(encb + (size_t)(2 * j + par) * ROWSTRIDE);

    const short* bh = wt_hi + (size_t)a_col * D_DIM + quad * 8;
    const short* bl = wt_lo + (size_t)a_col * D_DIM + quad * 8;

#pragma unroll 1
    for (int sub = 0; sub < N_SUB; ++sub) {
        // ---- stage cur -> LDS (split bf16) ----
#pragma unroll
        for (int j = 0; j < 8; ++j) {
            const int li = 2 * j + par;
            short4 h4, l4;
            split4(cur[j], h4, l4);
            *(short4*)&Ehi[li][po * 4] = h4;
            *(short4*)&Elo[li][po * 4] = l4;
        }
        __syncthreads();   // tile visible (also guards prior-iter LDS readers)

        // ---- prefetch next sub-chunk (latency hidden by MFMA below) ----
        if (sub + 1 < N_SUB) {
            const float* p = encb + (size_t)(sub + 1) * SUB_L * ROWSTRIDE;
#pragma unroll
            for (int j = 0; j < 8; ++j)
                nxt[j] = *(const float4*)(p + (size_t)(2 * j + par) * ROWSTRIDE);
        }

        // ---- MFMA: P[l][a] = sum_d E[l][d] * We[d][a], split 3-product ----
        f32x4 acc = {0.f, 0.f, 0.f, 0.f};
#pragma unroll 4
        for (int s = 0; s < 16; ++s) {
            const int k = s * 32;
            const bf16x8 Ah = *(const bf16x8*)&Ehi[l15][k + quad * 8];
            const bf16x8 Al = *(const bf16x8*)&Elo[l15][k + quad * 8];
            const bf16x8 Bh = *(const bf16x8*)(bh + k);
            const bf16x8 Bl = *(const bf16x8*)(bl + k);
            acc = __builtin_amdgcn_mfma_f32_16x16x32_bf16(Ah, Bh, acc, 0, 0, 0);
            acc = __builtin_amdgcn_mfma_f32_16x16x32_bf16(Ah, Bl, acc, 0, 0, 0);
            acc = __builtin_amdgcn_mfma_f32_16x16x32_bf16(Al, Bh, acc, 0, 0, 0);
        }

        // ---- scores: C/D layout col=l15 (a), row=quad*4+r (l) ----
#pragma unroll
        for (int r = 0; r < 4; ++r) {
            float t = tanhf(acc[r] + hb0) * v0;
            t += __shfl_xor(t, 1);
            t += __shfl_xor(t, 2);
            t += __shfl_xor(t, 4);
            t += __shfl_xor(t, 8);
            if (l15 == 0) sred[quad * 4 + r][wave] = t;
        }
        __syncthreads();

        if (tid < SUB_L) {
            const int lg = c * CHUNK_L + sub * SUB_L + tid;
            float s = sred[tid][0] + sred[tid][1] + sred[tid][2] + sred[tid][3];
            s = (lg < len_b) ? (s + 1.0f) : -INFINITY;
            float m = s;
            m = fmaxf(m, __shfl_xor(m, 1));
            m = fmaxf(m, __shfl_xor(m, 2));
            m = fmaxf(m, __shfl_xor(m, 4));
            m = fmaxf(m, __shfl_xor(m, 8));
            const float w = (m == -INFINITY) ? 0.f : expf(s - m);
            wl[tid] = w;
            float z = w;
            z += __shfl_xor(z, 1);
            z += __shfl_xor(z, 2);
            z += __shfl_xor(z, 4);
            z += __shfl_xor(z, 8);
            if (tid == 0) { msc[0] = m; msc[1] = z; }
        }
        __syncthreads();

        // ---- online-softmax merge + weighted accumulation from registers ----
        const float m_sub = msc[0], Z_sub = msc[1];
        const float mN = fmaxf(mA, m_sub);
        const float cA = (mA == -INFINITY) ? 0.f : expf(mA - mN);
        const float cS = (m_sub == -INFINITY) ? 0.f : expf(m_sub - mN);
        Oacc.x *= cA; Oacc.y *= cA; Oacc.z *= cA; Oacc.w *= cA;
#pragma unroll
        for (int j = 0; j < 8; ++j) {
            const float w = cS * wl[2 * j + par];
            Oacc.x += w * cur[j].x;
            Oacc.y += w * cur[j].y;
            Oacc.z += w * cur[j].z;
            Oacc.w += w * cur[j].w;
        }
        ZA = cA * ZA + cS * Z_sub;
        mA = mN;

#pragma unroll
        for (int j = 0; j < 8; ++j) cur[j] = nxt[j];
    }

    // ---- merge the two parity halves, write chunk partials ----
    if (par == 0) *(float4*)&ored[po * 4] = Oacc;
    __syncthreads();
    if (par == 1) {
        const float4 o0 = *(const float4*)&ored[po * 4];
        float4 r;
        r.x = o0.x + Oacc.x;
        r.y = o0.y + Oacc.y;
        r.z = o0.z + Oacc.z;
        r.w = o0.w + Oacc.w;
        *(float4*)(Om + ((size_t)b * N_CHUNK + c) * D_DIM + po * 4) = r;
    }
    if (tid == 0) {
        mz[((size_t)b * N_CHUNK + c) * 2 + 0] = mA;
        mz[((size_t)b * N_CHUNK + c) * 2 + 1] = ZA;
    }
}

// ---------------------------------------------------------------------------
// Combine: merge 32 chunk partials per b -> out[b][d]
// ---------------------------------------------------------------------------
__global__ __launch_bounds__(256) void combine_kernel(
    const float* __restrict__ Om, const float* __restrict__ mz,
    float* __restrict__ out) {
    const int b = blockIdx.x;
    const int tid = threadIdx.x;
    __shared__ float coef[N_CHUNK];
    __shared__ float sinv;

    if (tid < 32) {
        const float m = mz[((size_t)b * N_CHUNK + tid) * 2 + 0];
        const float Z = mz[((size_t)b * N_CHUNK + tid) * 2 + 1];
        float mm = m;
        mm = fmaxf(mm, __shfl_xor(mm, 1));
        mm = fmaxf(mm, __shfl_xor(mm, 2));
        mm = fmaxf(mm, __shfl_xor(mm, 4));
        mm = fmaxf(mm, __shfl_xor(mm, 8));
        mm = fmaxf(mm, __shfl_xor(mm, 16));
        const float cc = (m == -INFINITY) ? 0.f : expf(m - mm);
        coef[tid] = cc;
        float s = cc * Z;
        s += __shfl_xor(s, 1);
        s += __shfl_xor(s, 2);
        s += __shfl_xor(s, 4);
        s += __shfl_xor(s, 8);
        s += __shfl_xor(s, 16);
        if (tid == 0) sinv = 1.0f / s;
    }
    __syncthreads();

    const float* base = Om + (size_t)b * N_CHUNK * D_DIM + tid * 2;
    float ox = 0.f, oy = 0.f;
#pragma unroll 8
    for (int cc = 0; cc < N_CHUNK; ++cc) {
        const float2 x = *(const float2*)(base + cc * D_DIM);
        ox += coef[cc] * x.x;
        oy += coef[cc] * x.y;
    }
    const float s = sinv;
    *(float2*)(out + (size_t)b * D_DIM + tid * 2) = make_float2(ox * s, oy * s);
}

// ===========================================================================
extern "C" void kernel_launch(void* const* d_in, const int* in_sizes, int n_in,
                              void* d_out, int out_size, void* d_ws, size_t ws_size,
                              hipStream_t stream) {
    const float* enc    = (const float*)d_in[0];  // (L, B, 512)
    const int*   lens   = (const int*)d_in[1];    // (B,)
    const float* hidden = (const float*)d_in[2];  // (B, 512)
    const float* We     = (const float*)d_in[3];  // (512, 64)
    const float* battn  = (const float*)d_in[4];  // (64,)
    const float* Wh     = (const float*)d_in[5];  // (512, 64)
    const float* v      = (const float*)d_in[6];  // (64,)
    float* out = (float*)d_out;                   // (B, 512)

    // ws layout (bytes): hb @0 (16K) | wt_hi @16K (64K) | wt_lo @80K (64K)
    //                    | mz @144K (16K) | Om @160K (4 MB)
    char* w8 = (char*)d_ws;
    float* hb    = (float*)(w8 + 0);
    short* wt_hi = (short*)(w8 + 16 * 1024);
    short* wt_lo = (short*)(w8 + 80 * 1024);
    float* mz    = (float*)(w8 + 144 * 1024);
    float* Om    = (float*)(w8 + 160 * 1024);

    hb_kernel<<<B_DIM, A_DIM, 0, stream>>>(hidden, Wh, battn, hb);
    wt_kernel<<<(D_DIM * A_DIM) / 256, 256, 0, stream>>>(We, wt_hi, wt_lo);
    fused_kernel<<<dim3(N_CHUNK, B_DIM), 256, 0, stream>>>(
        enc, wt_hi, wt_lo, hb, v, lens, Om, mz);
    combine_kernel<<<B_DIM, 256, 0, stream>>>(Om, mz, out);
}